// Round 5
// baseline (571.730 us; speedup 1.0000x reference)
//
#include <hip/hip_runtime.h>

typedef __bf16 bf16;
typedef __bf16 bf16x4 __attribute__((ext_vector_type(4)));
typedef __bf16 bf16x8 __attribute__((ext_vector_type(8)));
typedef float  f32x4  __attribute__((ext_vector_type(4)));

#define MFMA16(a, b, c) __builtin_amdgcn_mfma_f32_16x16x32_bf16((a), (b), (c), 0, 0, 0)

constexpr int N_NODES = 50000;
constexpr int N_EDGES = 800000;
constexpr int D = 64;

// ---------------- fast-path workspace layout (~112.7 MB) ----------------
constexpr size_t OFF_FBUF   = 0;                       // bf16[N_NODES*D]   6.4e6 B
constexpr size_t OFF_H2     = 6400000;                 // bf16[N_EDGES*D] 102.4e6 B
constexpr size_t OFF_IPOS   = 108800000;               // (unused since R5)
constexpr size_t OFF_ROWPTR = 112000000;               // int[N_NODES+1]
constexpr size_t OFF_CURSOR = 112200064;               // int[N_NODES]
constexpr size_t OFF_COUNTS = 112400064;               // int[N_NODES]
constexpr size_t OFF_WBF    = 112600064;               // bf16[28672]
constexpr size_t OFF_FLAGS  = 112657408;               // int[2]
constexpr size_t WS_FAST_NEED = 112700000;

// ---------------- slow-path fallback layout (~12.9 MB) --------------
constexpr size_t S_SBUF  = 0;                          // f32[N_NODES*D] 12.8e6 B
constexpr size_t S_FLAGS = 12800000;

// strides (elements). LDS tiles padded: multiple of 8 elems (16B align for
// ds_read_b128); stride in dwords != 0 mod 32 (2-way bank alias only).
constexpr int XS_STRIDE = 200;
constexpr int HS_STRIDE = 72;
constexpr int X2_STRIDE = 136;
constexpr int W1_STRIDE = 200;   // 192 + 8 pad
constexpr int W3_STRIDE = 136;   // 128 + 8 pad

// ---------------------------------------------------------------------------
// Dtype detection (proven): flags[0]=1 -> f32 arrays; flags[1]=1 -> i64 idx.
// ---------------------------------------------------------------------------
__global__ void detect_kernel(const void* __restrict__ feat,
                              const void* __restrict__ eidx,
                              int* __restrict__ flags)
{
    __shared__ int c_bf[64], c_nz[64];
    const int t = threadIdx.x;
    const unsigned short* h = (const unsigned short*)feat;
    int c = 0;
    #pragma unroll
    for (int j = 0; j < 8; ++j) {
        const unsigned short v = h[(t * 8 + j) * 2];
        const int e8 = (v >> 7) & 0xFF;
        c += (e8 >= 97 && e8 <= 157) ? 1 : 0;
    }
    c_bf[t] = c;
    const int* ei = (const int*)eidx;
    int nz = 0;
    #pragma unroll
    for (int j = 0; j < 2; ++j)
        nz += (ei[(t * 2 + j) * 2 + 1] != 0) ? 1 : 0;
    c_nz[t] = nz;
    __syncthreads();
    if (t == 0) {
        int s = 0, s2 = 0;
        for (int i = 0; i < 64; ++i) { s += c_bf[i]; s2 += c_nz[i]; }
        flags[0] = (s < 384) ? 1 : 0;
        flags[1] = (s2 < 4) ? 1 : 0;
    }
}

__device__ inline bf16x8 ld8(const void* base, size_t off, int f32f) {
    if (f32f) {
        const float* p = (const float*)base + off;
        const float4 a = *(const float4*)p;
        const float4 b = *(const float4*)(p + 4);
        bf16x8 r;
        r[0] = (bf16)a.x; r[1] = (bf16)a.y; r[2] = (bf16)a.z; r[3] = (bf16)a.w;
        r[4] = (bf16)b.x; r[5] = (bf16)b.y; r[6] = (bf16)b.z; r[7] = (bf16)b.w;
        return r;
    }
    return *(const bf16x8*)((const bf16*)base + off);
}

__device__ inline float ldf(const void* base, int i, int f32f) {
    return f32f ? ((const float*)base)[i] : (float)((const bf16*)base)[i];
}

__device__ inline int gidx(const void* e, size_t i, int i64f) {
    return i64f ? (int)((const long long*)e)[i] : ((const int*)e)[i];
}

// ---------------------------------------------------------------------------
// Weight pre-conversion: wbf = bf16[ W1(12288) | W2(4096) | W3(8192) | W4(4096) ]
// ---------------------------------------------------------------------------
__global__ void prep_kernel(const void* __restrict__ W1, const void* __restrict__ W2,
                            const void* __restrict__ W3, const void* __restrict__ W4,
                            bf16* __restrict__ wbf, const int* __restrict__ flags)
{
    const int F32 = flags[0];
    for (int i = threadIdx.x; i < 28672; i += 256) {
        const void* src; int off;
        if (i < 12288)      { src = W1; off = i; }
        else if (i < 16384) { src = W2; off = i - 12288; }
        else if (i < 24576) { src = W3; off = i - 16384; }
        else                { src = W4; off = i - 24576; }
        wbf[i] = F32 ? (bf16)((const float*)src)[off] : ((const bf16*)src)[off];
    }
}

// ---------------------------------------------------------------------------
// R5: conv_feat fused with hist (exactly 800000 threads each; saves a launch
// and an eidx pass). Thread i converts feat quad i AND histograms edge i.
// ---------------------------------------------------------------------------
__global__ void conv_hist_kernel(const void* __restrict__ feat, bf16* __restrict__ fbuf,
                                 const void* __restrict__ eidx, int* __restrict__ counts,
                                 const int* __restrict__ flags)
{
    const int F32 = flags[0], I64 = flags[1];
    const int i = blockIdx.x * 256 + threadIdx.x;     // 0..799999
    if (F32) {
        const float4 v = ((const float4*)feat)[i];
        bf16x4 r; r[0] = (bf16)v.x; r[1] = (bf16)v.y; r[2] = (bf16)v.z; r[3] = (bf16)v.w;
        ((bf16x4*)fbuf)[i] = r;
    } else {
        ((bf16x4*)fbuf)[i] = ((const bf16x4*)feat)[i];
    }
    atomicAdd(&counts[gidx(eidx, (size_t)i, I64)], 1);
}

__global__ void scan_kernel(const int* __restrict__ counts, int* __restrict__ rowptr,
                            int* __restrict__ cursor)
{
    __shared__ int part[256];
    const int t = threadIdx.x;
    const int base = t * 196;            // 196*4B = 784B, 16B-aligned; 50000%4==0
    int s = 0;
    for (int g = 0; g < 49; ++g) {
        const int idx = base + g * 4;
        if (idx < N_NODES) {
            const int4 v = *(const int4*)&counts[idx];
            s += v.x + v.y + v.z + v.w;
        }
    }
    part[t] = s;
    __syncthreads();
    if (t == 0) {
        int acc = 0;
        for (int i = 0; i < 256; ++i) { const int v = part[i]; part[i] = acc; acc += v; }
        rowptr[N_NODES] = acc;
    }
    __syncthreads();
    int acc = part[t];
    for (int g = 0; g < 49; ++g) {
        const int idx = base + g * 4;
        if (idx < N_NODES) {
            const int4 v = *(const int4*)&counts[idx];
            int4 r;
            r.x = acc;
            r.y = acc + v.x;
            r.z = acc + v.x + v.y;
            r.w = acc + v.x + v.y + v.z;
            acc += v.x + v.y + v.z + v.w;
            *(int4*)&rowptr[idx] = r;
            *(int4*)&cursor[idx] = r;
        }
    }
}

// ---------------------------------------------------------------------------
// FAST edge kernel (R5). Changes vs R4 (edge was 137us, all pipes <26%,
// VGPR=68 => compiler serialized the A-gathers; LDS 53KB => 3 blocks/CU):
//  - explicit prefetch of ALL 12 A-fragments into registers (forces MLP)
//  - W2 B-fragments in registers (loaded post-GEMM1), W2l LDS dropped
//  - hs shrunk to 16 rows/wave, reused sequentially per M-tile
//  => LDS 34.5KB -> 4 blocks/CU (16 waves), launch_bounds(256,4) (VGPR<=128)
//  - CSR slot atomics inline (ips = atomicAdd(cursor[src])); fill_kernel gone.
//    Slot order within a row is arbitrary -> atomic here is equivalent.
// ---------------------------------------------------------------------------
__global__ __launch_bounds__(256, 4) void edge_fast(
    const bf16* __restrict__ fbuf, const void* __restrict__ eidx,
    const void* __restrict__ efeat,
    const bf16* __restrict__ wbf, const void* __restrict__ b1, const void* __restrict__ b2,
    int* __restrict__ cursor, bf16* __restrict__ h2ws, const int* __restrict__ flags)
{
    __shared__ bf16 W1l[64 * W1_STRIDE];   // 25600 B
    __shared__ bf16 hs[4][16 * 72];        //  9216 B (roundtrip + store staging)
    __shared__ int  ips[4][32];            //   512 B (CSR slots, wave-private)

    const int t    = threadIdx.x;
    const int wave = t >> 6;
    const int lane = t & 63;
    const int lrow = lane & 15;
    const int quad = lane >> 4;
    const int e0   = blockIdx.x * 128 + wave * 32;   // this wave's 32 edges
    const int F32  = flags[0], I64 = flags[1];

    // ---- stage W1 (12288 elems) into LDS, bf16x8 chunks ----
    #pragma unroll
    for (int it = 0; it < 6; ++it) {
        const int idx = it * 256 + t;           // 0..1535
        const int row = idx / 24;               // 192/8 = 24 chunks per row
        const int col = (idx - row * 24) * 8;
        *(bf16x8*)&W1l[row * W1_STRIDE + col] = *(const bf16x8*)&wbf[row * 192 + col];
    }

    const int eA   = e0 + lrow;
    const int eB   = e0 + 16 + lrow;
    const int srcA = gidx(eidx, (size_t)eA, I64);
    const int dstA = gidx(eidx, (size_t)N_EDGES + eA, I64);
    const int srcB = gidx(eidx, (size_t)eB, I64);
    const int dstB = gidx(eidx, (size_t)N_EDGES + eB, I64);

    // CSR slot atomics: one per edge (lanes 0..31 cover edges e0..e0+31).
    // Issued early; results consumed only at the final stores.
    if (lane < 32) {
        const int s = (lane < 16) ? srcA : srcB;
        ips[wave][lane] = atomicAdd(&cursor[s], 1);
    }

    // ---- explicit A-prefetch: all 12 fragments in flight ----
    bf16x8 aA[6], aB[6];
    #pragma unroll
    for (int k = 0; k < 6; ++k) {
        const int po = (k & 1) * 32 + quad * 8;
        if (k < 2) {
            aA[k] = *(const bf16x8*)&fbuf[(size_t)srcA * D + po];
            aB[k] = *(const bf16x8*)&fbuf[(size_t)srcB * D + po];
        } else if (k < 4) {
            aA[k] = ld8(efeat, (size_t)eA * D + po, F32);
            aB[k] = ld8(efeat, (size_t)eB * D + po, F32);
        } else {
            aA[k] = *(const bf16x8*)&fbuf[(size_t)dstA * D + po];
            aB[k] = *(const bf16x8*)&fbuf[(size_t)dstB * D + po];
        }
    }

    __syncthreads();    // W1l ready (A-loads issued before the barrier drain)

    // GEMM1: K=192, M-blocked x2; B from LDS, A from registers.
    f32x4 acc[2][4] = {
        {{0,0,0,0},{0,0,0,0},{0,0,0,0},{0,0,0,0}},
        {{0,0,0,0},{0,0,0,0},{0,0,0,0},{0,0,0,0}}
    };
    #pragma unroll
    for (int k = 0; k < 6; ++k) {
        #pragma unroll
        for (int n = 0; n < 4; ++n) {
            const bf16x8 b = *(const bf16x8*)&W1l[(n * 16 + lrow) * W1_STRIDE + k * 32 + quad * 8];
            acc[0][n] = MFMA16(aA[k], b, acc[0][n]);
            acc[1][n] = MFMA16(aB[k], b, acc[1][n]);
        }
    }

    // W2 B-fragments -> registers (L2/L3-resident; hidden under hs roundtrip).
    bf16x8 w2r[2][4];
    #pragma unroll
    for (int k = 0; k < 2; ++k)
        #pragma unroll
        for (int n = 0; n < 4; ++n)
            w2r[k][n] = *(const bf16x8*)&wbf[12288 + (n * 16 + lrow) * 64 + k * 32 + quad * 8];

    // Per M-tile: ReLU+b1 -> hs -> GEMM2 (hs reused; wave-private, DS FIFO-safe).
    f32x4 acc2[2][4];
    #pragma unroll
    for (int m = 0; m < 2; ++m) {
        #pragma unroll
        for (int n = 0; n < 4; ++n) {
            const int col  = n * 16 + lrow;
            const float bb = ldf(b1, col, F32);
            #pragma unroll
            for (int r = 0; r < 4; ++r) {
                float v = acc[m][n][r] + bb;
                v = v > 0.f ? v : 0.f;
                hs[wave][(quad * 4 + r) * 72 + col] = (bf16)v;
            }
        }
        #pragma unroll
        for (int n = 0; n < 4; ++n) acc2[m][n] = f32x4{0, 0, 0, 0};
        #pragma unroll
        for (int k = 0; k < 2; ++k) {
            const bf16x8 a = *(const bf16x8*)&hs[wave][lrow * 72 + k * 32 + quad * 8];
            #pragma unroll
            for (int n = 0; n < 4; ++n)
                acc2[m][n] = MFMA16(a, w2r[k][n], acc2[m][n]);
        }
    }

    // h2 + b2 -> hs, then 32B/lane scattered store at ips (scatter proven free).
    const int row = lane >> 2;          // 0..15 (edge row within M-tile)
    const int seg = lane & 3;           // 16-col segment
    #pragma unroll
    for (int m = 0; m < 2; ++m) {
        #pragma unroll
        for (int n = 0; n < 4; ++n) {
            const int col  = n * 16 + lrow;
            const float bb = ldf(b2, col, F32);
            #pragma unroll
            for (int r = 0; r < 4; ++r)
                hs[wave][(quad * 4 + r) * 72 + col] = (bf16)(acc2[m][n][r] + bb);
        }
        const int ip  = ips[wave][m * 16 + row];
        const bf16x8 v0 = *(const bf16x8*)&hs[wave][row * 72 + seg * 16];
        const bf16x8 v1 = *(const bf16x8*)&hs[wave][row * 72 + seg * 16 + 8];
        *(bf16x8*)&h2ws[(size_t)ip * D + seg * 16]     = v0;
        *(bf16x8*)&h2ws[(size_t)ip * D + seg * 16 + 8] = v1;
    }
}

// ---------------------------------------------------------------------------
// FAST node kernel (R5): contiguous CSR segment-sum (8-deep unroll), W3 in
// LDS, W4 in registers, h3 aliased into dead xs rows (wave-partitioned).
// LDS 34.8KB -> 4 blocks/CU, launch_bounds(256,4).
// ---------------------------------------------------------------------------
__global__ __launch_bounds__(256, 4) void node_fast(
    const bf16* __restrict__ fbuf, const bf16* __restrict__ h2ws,
    const int* __restrict__ rowptr,
    const bf16* __restrict__ wbf, const void* __restrict__ b3, const void* __restrict__ b4,
    void* __restrict__ out, const int* __restrict__ flags)
{
    __shared__ bf16 xs[64 * X2_STRIDE];    // 17408 B (f|s; later rows reused for h3)
    __shared__ bf16 W3l[64 * W3_STRIDE];   // 17408 B

    const int t  = threadIdx.x;
    const int r0 = blockIdx.x * 64;
    const int F32 = flags[0];

    // ---- stage W3 (8192 elems) ----
    #pragma unroll
    for (int it = 0; it < 4; ++it) {
        const int idx = it * 256 + t;           // 0..1023
        const int row = idx >> 4;               // 128/8 = 16 chunks per row
        const int col = (idx & 15) * 8;
        *(bf16x8*)&W3l[row * W3_STRIDE + col] = *(const bf16x8*)&wbf[16384 + row * 128 + col];
    }

    // segment sum: thread t -> node r0 + (t>>2), col segment (t&3)*16
    {
        const int nloc = t >> 2;
        const int node = r0 + nloc;
        const int seg  = t & 3;
        float accv[16];
        #pragma unroll
        for (int i = 0; i < 16; ++i) accv[i] = 0.f;
        bf16x8 f0 = {0,0,0,0,0,0,0,0}, f1 = {0,0,0,0,0,0,0,0};
        if (node < N_NODES) {
            f0 = *(const bf16x8*)&fbuf[(size_t)node * D + seg * 16];
            f1 = *(const bf16x8*)&fbuf[(size_t)node * D + seg * 16 + 8];
            const int jb = rowptr[node], je = rowptr[node + 1];
            int j = jb;
            for (; j + 8 <= je; j += 8) {
                bf16x8 v[16];
                #pragma unroll
                for (int u = 0; u < 8; ++u) {
                    v[2 * u]     = *(const bf16x8*)&h2ws[(size_t)(j + u) * D + seg * 16];
                    v[2 * u + 1] = *(const bf16x8*)&h2ws[(size_t)(j + u) * D + seg * 16 + 8];
                }
                #pragma unroll
                for (int u = 0; u < 8; ++u) {
                    #pragma unroll
                    for (int i = 0; i < 8; ++i) {
                        accv[i]     += (float)v[2 * u][i];
                        accv[i + 8] += (float)v[2 * u + 1][i];
                    }
                }
            }
            for (; j + 2 <= je; j += 2) {
                const bf16x8 a0 = *(const bf16x8*)&h2ws[(size_t)j * D + seg * 16];
                const bf16x8 a1 = *(const bf16x8*)&h2ws[(size_t)j * D + seg * 16 + 8];
                const bf16x8 c0 = *(const bf16x8*)&h2ws[(size_t)(j + 1) * D + seg * 16];
                const bf16x8 c1 = *(const bf16x8*)&h2ws[(size_t)(j + 1) * D + seg * 16 + 8];
                #pragma unroll
                for (int i = 0; i < 8; ++i) {
                    accv[i]     += (float)a0[i] + (float)c0[i];
                    accv[i + 8] += (float)a1[i] + (float)c1[i];
                }
            }
            if (j < je) {
                const bf16x8 a0 = *(const bf16x8*)&h2ws[(size_t)j * D + seg * 16];
                const bf16x8 a1 = *(const bf16x8*)&h2ws[(size_t)j * D + seg * 16 + 8];
                #pragma unroll
                for (int i = 0; i < 8; ++i) {
                    accv[i]     += (float)a0[i];
                    accv[i + 8] += (float)a1[i];
                }
            }
        }
        bf16x8 s0, s1;
        #pragma unroll
        for (int i = 0; i < 8; ++i) {
            s0[i] = (bf16)((float)f0[i] + accv[i]);
            s1[i] = (bf16)((float)f1[i] + accv[i + 8]);
        }
        *(bf16x8*)&xs[nloc * X2_STRIDE + seg * 16]          = f0;
        *(bf16x8*)&xs[nloc * X2_STRIDE + seg * 16 + 8]      = f1;
        *(bf16x8*)&xs[nloc * X2_STRIDE + 64 + seg * 16]     = s0;
        *(bf16x8*)&xs[nloc * X2_STRIDE + 64 + seg * 16 + 8] = s1;
    }
    __syncthreads();

    const int wave = t >> 6;
    const int lane = t & 63;
    const int m0   = wave * 16;
    const int lrow = lane & 15;
    const int quad = lane >> 4;

    // W4 B-fragments -> registers (issued before GEMM3 to hide L2/L3 latency).
    bf16x8 w4r[2][4];
    #pragma unroll
    for (int k = 0; k < 2; ++k)
        #pragma unroll
        for (int n = 0; n < 4; ++n)
            w4r[k][n] = *(const bf16x8*)&wbf[24576 + (n * 16 + lrow) * 64 + k * 32 + quad * 8];

    // GEMM3: K=128
    f32x4 acc[4] = {{0,0,0,0},{0,0,0,0},{0,0,0,0},{0,0,0,0}};
    #pragma unroll
    for (int k = 0; k < 4; ++k) {
        const bf16x8 a = *(const bf16x8*)&xs[(m0 + lrow) * X2_STRIDE + k * 32 + quad * 8];
        #pragma unroll
        for (int n = 0; n < 4; ++n) {
            const bf16x8 b = *(const bf16x8*)&W3l[(n * 16 + lrow) * W3_STRIDE + k * 32 + quad * 8];
            acc[n] = MFMA16(a, b, acc[n]);
        }
    }

    // ReLU + b3 -> h3 aliased into this wave's (now dead) xs rows, cols 0..63.
    #pragma unroll
    for (int n = 0; n < 4; ++n) {
        const int col  = n * 16 + lrow;
        const float bb = ldf(b3, col, F32);
        #pragma unroll
        for (int r = 0; r < 4; ++r) {
            float v = acc[n][r] + bb;
            v = v > 0.f ? v : 0.f;
            xs[(m0 + quad * 4 + r) * X2_STRIDE + col] = (bf16)v;
        }
    }

    // GEMM4: K=64 (A from aliased xs rows; B from registers)
    f32x4 acc2[4] = {{0,0,0,0},{0,0,0,0},{0,0,0,0},{0,0,0,0}};
    #pragma unroll
    for (int k = 0; k < 2; ++k) {
        const bf16x8 a = *(const bf16x8*)&xs[(m0 + lrow) * X2_STRIDE + k * 32 + quad * 8];
        #pragma unroll
        for (int n = 0; n < 4; ++n)
            acc2[n] = MFMA16(a, w4r[k][n], acc2[n]);
    }

    #pragma unroll
    for (int n = 0; n < 4; ++n) {
        const int col  = n * 16 + lrow;
        const float bb = ldf(b4, col, F32);
        #pragma unroll
        for (int r = 0; r < 4; ++r) {
            const int node = r0 + m0 + quad * 4 + r;
            if (node < N_NODES) {
                const float v = acc2[n][r] + bb;
                if (F32) ((float*)out)[(size_t)node * D + col] = v;
                else     ((bf16*)out)[(size_t)node * D + col] = (bf16)v;
            }
        }
    }
}

// ---------------------------------------------------------------------------
// SLOW fallback = proven kernels (global f32 atomic scatter), used only
// if ws_size is too small for the fast path.
// ---------------------------------------------------------------------------
constexpr int XSS_STRIDE = 200;

__global__ __launch_bounds__(256) void edge_slow(
    const void* __restrict__ feat, const void* __restrict__ eidx,
    const void* __restrict__ efeat,
    const void* __restrict__ W1, const void* __restrict__ b1,
    const void* __restrict__ W2, const void* __restrict__ b2,
    float* __restrict__ sbuf, const int* __restrict__ flags)
{
    __shared__ bf16 xs[64 * XSS_STRIDE];
    __shared__ bf16 h1s[64 * HS_STRIDE];
    __shared__ int  srcs[64];
    __shared__ int  fl[2];

    const int t  = threadIdx.x;
    const int e0 = blockIdx.x * 64;

    if (t < 2) fl[t] = flags[t];
    __syncthreads();
    const int F32 = fl[0], I64 = fl[1];

    if (t < 64) srcs[t] = gidx(eidx, e0 + t, I64);

    for (int i = t; i < 64 * 24; i += 256) {
        const int e    = i / 24;
        const int c    = i - e * 24;
        const int part = c >> 3;
        const int cc   = c & 7;
        size_t off;
        const void* base;
        if (part == 0)      { base = feat;  off = (size_t)gidx(eidx, e0 + e, I64) * D + cc * 8; }
        else if (part == 1) { base = efeat; off = (size_t)(e0 + e) * D + cc * 8; }
        else                { base = feat;  off = (size_t)gidx(eidx, (size_t)N_EDGES + e0 + e, I64) * D + cc * 8; }
        *(bf16x8*)&xs[e * XSS_STRIDE + part * 64 + cc * 8] = ld8(base, off, F32);
    }
    __syncthreads();

    const int wave = t >> 6;
    const int lane = t & 63;
    const int m0   = wave * 16;
    const int lrow = lane & 15;
    const int quad = lane >> 4;

    f32x4 acc[4] = {{0,0,0,0},{0,0,0,0},{0,0,0,0},{0,0,0,0}};
    #pragma unroll
    for (int k = 0; k < 6; ++k) {
        const bf16x8 a = *(const bf16x8*)&xs[(m0 + lrow) * XSS_STRIDE + k * 32 + quad * 8];
        #pragma unroll
        for (int n = 0; n < 4; ++n) {
            const bf16x8 b = ld8(W1, (size_t)(n * 16 + lrow) * 192 + k * 32 + quad * 8, F32);
            acc[n] = MFMA16(a, b, acc[n]);
        }
    }

    #pragma unroll
    for (int n = 0; n < 4; ++n) {
        const int col  = n * 16 + lrow;
        const float bb = ldf(b1, col, F32);
        #pragma unroll
        for (int r = 0; r < 4; ++r) {
            float v = acc[n][r] + bb;
            v = v > 0.f ? v : 0.f;
            h1s[(m0 + quad * 4 + r) * HS_STRIDE + col] = (bf16)v;
        }
    }
    __syncthreads();

    f32x4 acc2[4] = {{0,0,0,0},{0,0,0,0},{0,0,0,0},{0,0,0,0}};
    #pragma unroll
    for (int k = 0; k < 2; ++k) {
        const bf16x8 a = *(const bf16x8*)&h1s[(m0 + lrow) * HS_STRIDE + k * 32 + quad * 8];
        #pragma unroll
        for (int n = 0; n < 4; ++n) {
            const bf16x8 b = ld8(W2, (size_t)(n * 16 + lrow) * D + k * 32 + quad * 8, F32);
            acc2[n] = MFMA16(a, b, acc2[n]);
        }
    }

    #pragma unroll
    for (int n = 0; n < 4; ++n) {
        const int col  = n * 16 + lrow;
        const float bb = ldf(b2, col, F32);
        #pragma unroll
        for (int r = 0; r < 4; ++r) {
            const int e = m0 + quad * 4 + r;
            atomicAdd(&sbuf[(size_t)srcs[e] * D + col], acc2[n][r] + bb);
        }
    }
}

__global__ __launch_bounds__(256) void node_slow(
    const void* __restrict__ feat, const float* __restrict__ sbuf,
    const void* __restrict__ W3, const void* __restrict__ b3,
    const void* __restrict__ W4, const void* __restrict__ b4,
    void* __restrict__ out, const int* __restrict__ flags)
{
    __shared__ bf16 xs[64 * X2_STRIDE];
    __shared__ bf16 h3s[64 * HS_STRIDE];
    __shared__ int fl[1];

    const int t  = threadIdx.x;
    const int r0 = blockIdx.x * 64;

    if (t == 0) fl[0] = flags[0];
    __syncthreads();
    const int F32 = fl[0];

    for (int i = t; i < 64 * 8; i += 256) {
        const int r    = i >> 3;
        const int c    = i & 7;
        const int node = r0 + r;
        bf16x8 fv = {0,0,0,0,0,0,0,0};
        bf16x8 sv = {0,0,0,0,0,0,0,0};
        if (node < N_NODES) {
            fv = ld8(feat, (size_t)node * D + c * 8, F32);
            const float4 sa = *(const float4*)&sbuf[(size_t)node * D + c * 8];
            const float4 sb = *(const float4*)&sbuf[(size_t)node * D + c * 8 + 4];
            sv[0] = (bf16)((float)fv[0] + sa.x);
            sv[1] = (bf16)((float)fv[1] + sa.y);
            sv[2] = (bf16)((float)fv[2] + sa.z);
            sv[3] = (bf16)((float)fv[3] + sa.w);
            sv[4] = (bf16)((float)fv[4] + sb.x);
            sv[5] = (bf16)((float)fv[5] + sb.y);
            sv[6] = (bf16)((float)fv[6] + sb.z);
            sv[7] = (bf16)((float)fv[7] + sb.w);
        }
        *(bf16x8*)&xs[r * X2_STRIDE + c * 8]      = fv;
        *(bf16x8*)&xs[r * X2_STRIDE + 64 + c * 8] = sv;
    }
    __syncthreads();

    const int wave = t >> 6;
    const int lane = t & 63;
    const int m0   = wave * 16;
    const int lrow = lane & 15;
    const int quad = lane >> 4;

    f32x4 acc[4] = {{0,0,0,0},{0,0,0,0},{0,0,0,0},{0,0,0,0}};
    #pragma unroll
    for (int k = 0; k < 4; ++k) {
        const bf16x8 a = *(const bf16x8*)&xs[(m0 + lrow) * X2_STRIDE + k * 32 + quad * 8];
        #pragma unroll
        for (int n = 0; n < 4; ++n) {
            const bf16x8 b = ld8(W3, (size_t)(n * 16 + lrow) * 128 + k * 32 + quad * 8, F32);
            acc[n] = MFMA16(a, b, acc[n]);
        }
    }

    #pragma unroll
    for (int n = 0; n < 4; ++n) {
        const int col  = n * 16 + lrow;
        const float bb = ldf(b3, col, F32);
        #pragma unroll
        for (int r = 0; r < 4; ++r) {
            float v = acc[n][r] + bb;
            v = v > 0.f ? v : 0.f;
            h3s[(m0 + quad * 4 + r) * HS_STRIDE + col] = (bf16)v;
        }
    }
    __syncthreads();

    f32x4 acc2[4] = {{0,0,0,0},{0,0,0,0},{0,0,0,0},{0,0,0,0}};
    #pragma unroll
    for (int k = 0; k < 2; ++k) {
        const bf16x8 a = *(const bf16x8*)&h3s[(m0 + lrow) * HS_STRIDE + k * 32 + quad * 8];
        #pragma unroll
        for (int n = 0; n < 4; ++n) {
            const bf16x8 b = ld8(W4, (size_t)(n * 16 + lrow) * D + k * 32 + quad * 8, F32);
            acc2[n] = MFMA16(a, b, acc2[n]);
        }
    }

    #pragma unroll
    for (int n = 0; n < 4; ++n) {
        const int col  = n * 16 + lrow;
        const float bb = ldf(b4, col, F32);
        #pragma unroll
        for (int r = 0; r < 4; ++r) {
            const int node = r0 + m0 + quad * 4 + r;
            if (node < N_NODES) {
                const float v = acc2[n][r] + bb;
                if (F32) ((float*)out)[(size_t)node * D + col] = v;
                else     ((bf16*)out)[(size_t)node * D + col] = (bf16)v;
            }
        }
    }
}

extern "C" void kernel_launch(void* const* d_in, const int* in_sizes, int n_in,
                              void* d_out, int out_size, void* d_ws, size_t ws_size,
                              hipStream_t stream) {
    const void* feat  = d_in[0];
    const void* eidx  = d_in[1];
    const void* efeat = d_in[2];
    const void* W1    = d_in[3];
    const void* b1    = d_in[4];
    const void* W2    = d_in[5];
    const void* b2    = d_in[6];
    const void* W3    = d_in[7];
    const void* b3    = d_in[8];
    const void* W4    = d_in[9];
    const void* b4    = d_in[10];

    char* ws = (char*)d_ws;

    if (ws_size >= WS_FAST_NEED) {
        bf16* fbuf   = (bf16*)(ws + OFF_FBUF);
        bf16* h2ws   = (bf16*)(ws + OFF_H2);
        int*  rowptr = (int*)(ws + OFF_ROWPTR);
        int*  cursor = (int*)(ws + OFF_CURSOR);
        int*  counts = (int*)(ws + OFF_COUNTS);
        bf16* wbf    = (bf16*)(ws + OFF_WBF);
        int*  flags  = (int*)(ws + OFF_FLAGS);

        detect_kernel<<<1, 64, 0, stream>>>(feat, eidx, flags);
        hipMemsetAsync(counts, 0, (size_t)N_NODES * sizeof(int), stream);
        prep_kernel<<<1, 256, 0, stream>>>(W1, W2, W3, W4, wbf, flags);
        conv_hist_kernel<<<3125, 256, 0, stream>>>(feat, fbuf, eidx, counts, flags);
        scan_kernel<<<1, 256, 0, stream>>>(counts, rowptr, cursor);
        edge_fast<<<N_EDGES / 128, 256, 0, stream>>>(fbuf, eidx, efeat, wbf, b1, b2,
                                                     cursor, h2ws, flags);
        node_fast<<<(N_NODES + 63) / 64, 256, 0, stream>>>(fbuf, h2ws, rowptr,
                                                           wbf, b3, b4, d_out, flags);
    } else {
        float* sbuf  = (float*)(ws + S_SBUF);
        int*   flags = (int*)(ws + S_FLAGS);

        detect_kernel<<<1, 64, 0, stream>>>(feat, eidx, flags);
        hipMemsetAsync(sbuf, 0, (size_t)N_NODES * D * sizeof(float), stream);
        edge_slow<<<N_EDGES / 64, 256, 0, stream>>>(feat, eidx, efeat, W1, b1, W2, b2,
                                                    sbuf, flags);
        node_slow<<<(N_NODES + 63) / 64, 256, 0, stream>>>(feat, sbuf, W3, b3, W4, b4,
                                                           d_out, flags);
    }
}